// Round 1
// baseline (9577.170 us; speedup 1.0000x reference)
//
#include <hip/hip_runtime.h>
#include <math.h>

#define F_BN   1
#define F_RELU 2
#define F_RES  4

// ---------------------------------------------------------------------------
// conv1x1: grid (ceil(P/128), ceil(CO/32), N), block 256
// thread: lane=tid&63 -> pixels p0, p0+64 ; gq=tid>>6 -> 8-channel group
// ---------------------------------------------------------------------------
__global__ __launch_bounds__(256) void conv1x1_kernel(
    const float* __restrict__ in, const float* __restrict__ w,
    const float* __restrict__ bias,
    const float* __restrict__ g, const float* __restrict__ be,
    const float* __restrict__ m, const float* __restrict__ v,
    const float* __restrict__ resid, float* __restrict__ out,
    int CI, int CO, int P, int flags)
{
    __shared__ float wl[32][32];   // [ci_local][co_local]
    const int tid  = threadIdx.x;
    const int lane = tid & 63;
    const int gq   = tid >> 6;
    const int n    = blockIdx.z;
    const int p0   = blockIdx.x * 128 + lane;
    const int p1   = p0 + 64;
    const int cob  = blockIdx.y * 32;
    const bool v0 = p0 < P, v1 = p1 < P;
    const float* inb = in + (size_t)n * CI * P;

    float acc0[8], acc1[8];
#pragma unroll
    for (int j = 0; j < 8; ++j) { acc0[j] = 0.f; acc1[j] = 0.f; }

    for (int ci0 = 0; ci0 < CI; ci0 += 32) {
        __syncthreads();
#pragma unroll
        for (int i = 0; i < 4; ++i) {
            int idx = tid + i * 256;
            int cc = idx >> 5, col = idx & 31;
            int co = cob + col;
            wl[cc][col] = (co < CO) ? w[(size_t)co * CI + ci0 + cc] : 0.f;
        }
        __syncthreads();
#pragma unroll 8
        for (int cc = 0; cc < 32; ++cc) {
            const float* r = inb + (size_t)(ci0 + cc) * P;
            float x0 = v0 ? r[p0] : 0.f;
            float x1 = v1 ? r[p1] : 0.f;
            const float4* w4 = reinterpret_cast<const float4*>(&wl[cc][gq * 8]);
            float4 wa = w4[0], wb = w4[1];
            float wr[8];
            wr[0]=wa.x; wr[1]=wa.y; wr[2]=wa.z; wr[3]=wa.w;
            wr[4]=wb.x; wr[5]=wb.y; wr[6]=wb.z; wr[7]=wb.w;
#pragma unroll
            for (int j = 0; j < 8; ++j) {
                acc0[j] = fmaf(wr[j], x0, acc0[j]);
                acc1[j] = fmaf(wr[j], x1, acc1[j]);
            }
        }
    }

#pragma unroll
    for (int j = 0; j < 8; ++j) {
        int co = cob + gq * 8 + j;
        if (co < CO) {
            float b0 = bias[co];
            float r0 = acc0[j] + b0, r1 = acc1[j] + b0;
            if (flags & F_BN) {
                float scale = g[co] / sqrtf(v[co] + 1e-5f);
                float mm = m[co], bb = be[co];
                r0 = (r0 - mm) * scale + bb;
                r1 = (r1 - mm) * scale + bb;
            }
            if (flags & F_RES) {
                const float* rr = resid + ((size_t)n * CO + co) * P;
                if (v0) r0 += rr[p0];
                if (v1) r1 += rr[p1];
            }
            if (flags & F_RELU) { r0 = fmaxf(r0, 0.f); r1 = fmaxf(r1, 0.f); }
            float* ob = out + ((size_t)n * CO + co) * P;
            if (v0) ob[p0] = r0;
            if (v1) ob[p1] = r1;
        }
    }
}

// ---------------------------------------------------------------------------
// conv3x3 (pad=1): grid (row_tiles, CO/16, N), block 256, dynamic LDS
// spatial tile = NROWS rows x W; 3 pixels/thread; 16 output channels/block
// ---------------------------------------------------------------------------
__global__ __launch_bounds__(256) void conv3x3_kernel(
    const float* __restrict__ in, const float* __restrict__ w,
    const float* __restrict__ bias,
    const float* __restrict__ g, const float* __restrict__ be,
    const float* __restrict__ m, const float* __restrict__ v,
    float* __restrict__ out,
    int CI, int CO, int H, int W, int NROWS, int flags)
{
    extern __shared__ float smem[];
    const int W2  = W + 2;
    const int xsz = (NROWS + 2) * W2;        // per-ci staged plane
    float* xl  = smem;                        // [8][xsz]
    float* wlp = smem + 8 * xsz;              // [8][9][16]

    const int tid  = threadIdx.x;
    const int n    = blockIdx.z;
    const int row0 = blockIdx.x * NROWS;
    const int nrows = min(NROWS, H - row0);
    const int cob  = blockIdx.y * 16;
    const int tilepx = nrows * W;
    const int HW = H * W;

    int ly[3], lx[3]; bool pv[3];
#pragma unroll
    for (int k = 0; k < 3; ++k) {
        int p = tid + k * 256;
        pv[k] = p < tilepx;
        int pp = pv[k] ? p : 0;
        ly[k] = pp / W; lx[k] = pp - ly[k] * W;
    }

    float acc[3][16];
#pragma unroll
    for (int k = 0; k < 3; ++k)
#pragma unroll
        for (int j = 0; j < 16; ++j) acc[k][j] = 0.f;

    const float* inb = in + (size_t)n * CI * HW;

    for (int ci0 = 0; ci0 < CI; ci0 += 8) {
        __syncthreads();
        // stage input planes with halo (zero padded)
        for (int idx = tid; idx < 8 * xsz; idx += 256) {
            int cc = idx / xsz; int r = idx - cc * xsz;
            int ry = r / W2,   rx = r - ry * W2;
            int y = row0 + ry - 1, x = rx - 1;
            int ci = ci0 + cc;
            float val = 0.f;
            if (ci < CI && y >= 0 && y < H && x >= 0 && x < W)
                val = inb[(size_t)ci * HW + y * W + x];
            xl[idx] = val;
        }
        // stage weights: [cc][tap][16co]
        for (int idx = tid; idx < 8 * 144; idx += 256) {
            int cc = idx / 144; int r = idx - cc * 144;
            int tap = r >> 4;   int j = r & 15;
            int ci = ci0 + cc;  int co = cob + j;
            float val = 0.f;
            if (ci < CI && co < CO)
                val = w[((size_t)co * CI + ci) * 9 + tap];
            wlp[idx] = val;
        }
        __syncthreads();

#pragma unroll 1
        for (int cc = 0; cc < 8; ++cc) {
            const float* xc = xl + cc * xsz;
            const float* wc = wlp + cc * 144;
#pragma unroll
            for (int t = 0; t < 9; ++t) {
                const int ky = t / 3, kx = t - 3 * (t / 3);
                const float4* w4 = reinterpret_cast<const float4*>(wc + t * 16);
                float4 a = w4[0], b = w4[1], c = w4[2], d = w4[3];
                float wr[16];
                wr[0]=a.x; wr[1]=a.y; wr[2]=a.z; wr[3]=a.w;
                wr[4]=b.x; wr[5]=b.y; wr[6]=b.z; wr[7]=b.w;
                wr[8]=c.x; wr[9]=c.y; wr[10]=c.z; wr[11]=c.w;
                wr[12]=d.x; wr[13]=d.y; wr[14]=d.z; wr[15]=d.w;
#pragma unroll
                for (int k = 0; k < 3; ++k) {
                    float xv = xc[(ly[k] + ky) * W2 + lx[k] + kx];
#pragma unroll
                    for (int j = 0; j < 16; ++j)
                        acc[k][j] = fmaf(wr[j], xv, acc[k][j]);
                }
            }
        }
    }

#pragma unroll
    for (int k = 0; k < 3; ++k) {
        if (!pv[k]) continue;
        int y = row0 + ly[k], x = lx[k];
#pragma unroll
        for (int j = 0; j < 16; ++j) {
            int co = cob + j;
            if (co < CO) {
                float r0 = acc[k][j] + bias[co];
                if (flags & F_BN) {
                    float scale = g[co] / sqrtf(v[co] + 1e-5f);
                    r0 = (r0 - m[co]) * scale + be[co];
                }
                if (flags & F_RELU) r0 = fmaxf(r0, 0.f);
                out[((size_t)n * CO + co) * HW + y * W + x] = r0;
            }
        }
    }
}

// ---------------------------------------------------------------------------
// deconv (transposed conv): in (N,256,23,23), w (256,CO,4,4), stride 2, k=4,
// out 46x46 written into cat buffer (N,212,46,46) at channel offset ch_off.
// Each output pixel has 2x2 valid taps; ky = (oy&1)+2*ty.
// ---------------------------------------------------------------------------
__global__ __launch_bounds__(256) void deconv_kernel(
    const float* __restrict__ in, const float* __restrict__ w,
    const float* __restrict__ bias, float* __restrict__ out,
    int CO, int ch_off, int relu)
{
    __shared__ float xl[8 * 529];
    __shared__ float wl[8 * 256];   // [cc][ky*4+kx][16co]

    const int tid = threadIdx.x;
    const int n   = blockIdx.z;
    const int cob = blockIdx.y * 16;
    const int p   = blockIdx.x * 256 + tid;
    const bool pvalid = p < 2116;
    const int pp = pvalid ? p : 0;
    const int oy = pp / 46, ox = pp - oy * 46;

    int kyA[2], iyA[2], kxA[2], ixA[2];
    bool vyA[2], vxA[2];
#pragma unroll
    for (int t = 0; t < 2; ++t) {
        kyA[t] = (oy & 1) + 2 * t;
        int num = oy + kyA[t] - 2;
        iyA[t] = num >> 1;
        vyA[t] = (num >= 0) && (iyA[t] < 23);
        kxA[t] = (ox & 1) + 2 * t;
        int numx = ox + kxA[t] - 2;
        ixA[t] = numx >> 1;
        vxA[t] = (numx >= 0) && (ixA[t] < 23);
    }

    float acc[16];
#pragma unroll
    for (int j = 0; j < 16; ++j) acc[j] = 0.f;

    const float* inb = in + (size_t)n * 256 * 529;

    for (int ci0 = 0; ci0 < 256; ci0 += 8) {
        __syncthreads();
        for (int idx = tid; idx < 8 * 529; idx += 256) {
            int cc = idx / 529; int r = idx - cc * 529;
            xl[idx] = inb[(size_t)(ci0 + cc) * 529 + r];
        }
        for (int idx = tid; idx < 8 * 256; idx += 256) {
            int cc = idx >> 8; int r = idx & 255;
            int tap = r >> 4;  int j = r & 15;
            int ky = tap >> 2, kx = tap & 3;
            int co = cob + j;
            float val = 0.f;
            if (co < CO)   // w[ci][co][3-ky][3-kx]
                val = w[((size_t)(ci0 + cc) * CO + co) * 16 + (3 - ky) * 4 + (3 - kx)];
            wl[idx] = val;
        }
        __syncthreads();

#pragma unroll 1
        for (int cc = 0; cc < 8; ++cc) {
            const float* xc = xl + cc * 529;
            const float* wc = wl + cc * 256;
#pragma unroll
            for (int ty = 0; ty < 2; ++ty)
#pragma unroll
            for (int tx = 0; tx < 2; ++tx) {
                bool vt = vyA[ty] && vxA[tx];
                int xi = vt ? (iyA[ty] * 23 + ixA[tx]) : 0;
                float xv = xc[xi];
                xv = vt ? xv : 0.f;
                const float4* w4 = reinterpret_cast<const float4*>(
                    wc + (kyA[ty] * 4 + kxA[tx]) * 16);
                float4 a = w4[0], b = w4[1], c = w4[2], d = w4[3];
                float wr[16];
                wr[0]=a.x; wr[1]=a.y; wr[2]=a.z; wr[3]=a.w;
                wr[4]=b.x; wr[5]=b.y; wr[6]=b.z; wr[7]=b.w;
                wr[8]=c.x; wr[9]=c.y; wr[10]=c.z; wr[11]=c.w;
                wr[12]=d.x; wr[13]=d.y; wr[14]=d.z; wr[15]=d.w;
#pragma unroll
                for (int j = 0; j < 16; ++j)
                    acc[j] = fmaf(wr[j], xv, acc[j]);
            }
        }
    }

    if (pvalid) {
#pragma unroll
        for (int j = 0; j < 16; ++j) {
            int co = cob + j;
            if (co < CO) {
                float r0 = acc[j] + bias[co];
                if (relu) r0 = fmaxf(r0, 0.f);
                out[((size_t)n * 212 + (ch_off + co)) * 2116 + p] = r0;
            }
        }
    }
}

// ---------------------------------------------------------------------------
// out3 = sqrt(out1[3j]^2 + out1[3j+1]^2 + out1[3j+2]^2) -> cat channel 191+j
// cat: (64, 212, 2116)
// ---------------------------------------------------------------------------
__global__ __launch_bounds__(256) void out3_kernel(float* __restrict__ cat)
{
    int idx = blockIdx.x * 256 + threadIdx.x;
    if (idx >= 64 * 21 * 2116) return;
    int n = idx / (21 * 2116);
    int r = idx - n * (21 * 2116);
    int j = r / 2116;
    int p = r - j * 2116;
    size_t base = (size_t)n * 212 * 2116;
    float a = cat[base + (size_t)(3 * j + 0) * 2116 + p];
    float b = cat[base + (size_t)(3 * j + 1) * 2116 + p];
    float c = cat[base + (size_t)(3 * j + 2) * 2116 + p];
    cat[base + (size_t)(191 + j) * 2116 + p] = sqrtf(a * a + b * b + c * c);
}

// ---------------------------------------------------------------------------
// Final argmax/gather. h: (64,112,46,46) viewed as (64,4,W'=46,H'=46,K=28).
// grid (28, 64), block 64 (one wave). Thread t owns h'=t (<46): max over w'.
// Then shuffle-reduce over h' with first-index tie-break (matches jnp.argmax).
// ---------------------------------------------------------------------------
__global__ __launch_bounds__(64) void argmax_kernel(
    const float* __restrict__ h, float* __restrict__ outp)
{
    const int k = blockIdx.x;
    const int n = blockIdx.y;
    const int t = threadIdx.x;
    const float* b = h + (size_t)n * 236992;   // 112*2116 = 4*59248

    float best = -INFINITY; int bw = 0; int bh = t;
    if (t < 46) {
        for (int wq = 0; wq < 46; ++wq) {
            float vv = b[wq * 1288 + t * 28 + k];
            if (vv > best) { best = vv; bw = wq; }   // strict > = first index
        }
    }
#pragma unroll
    for (int off = 32; off > 0; off >>= 1) {
        float ov = __shfl_down(best, off);
        int  oh  = __shfl_down(bh, off);
        int  ow  = __shfl_down(bw, off);
        if (ov > best || (ov == best && oh < bh)) { best = ov; bh = oh; bw = ow; }
    }
    if (t == 0) {
        int o1 = bw * 1288 + bh * 28 + k;
        float vx = b[1 * 59248 + o1];
        float vy = b[2 * 59248 + o1];
        float vz = b[3 * 59248 + o1];
        float* o = outp + (size_t)n * 84 + k * 3;
        o[0] = vx; o[1] = vy; o[2] = vz;
    }
}

// ---------------------------------------------------------------------------
extern "C" void kernel_launch(void* const* d_in, const int* in_sizes, int n_in,
                              void* d_out, int out_size, void* d_ws, size_t ws_size,
                              hipStream_t stream)
{
    const float* x   = (const float*)d_in[0];
    const float* w1  = (const float*)d_in[1];
    const float* rb1 = (const float*)d_in[2];
    const float* g1  = (const float*)d_in[3];
    const float* be1 = (const float*)d_in[4];
    const float* m1  = (const float*)d_in[5];
    const float* v1  = (const float*)d_in[6];
    const float* w2  = (const float*)d_in[7];
    const float* rb2 = (const float*)d_in[8];
    const float* g2  = (const float*)d_in[9];
    const float* be2 = (const float*)d_in[10];
    const float* m2  = (const float*)d_in[11];
    const float* v2  = (const float*)d_in[12];
    const float* w3  = (const float*)d_in[13];
    const float* rb3 = (const float*)d_in[14];
    const float* b1w = (const float*)d_in[15];
    const float* b1b = (const float*)d_in[16];
    const float* b2w = (const float*)d_in[17];
    const float* b2b = (const float*)d_in[18];
    const float* b3w = (const float*)d_in[19];
    const float* b3b = (const float*)d_in[20];
    const float* c1w = (const float*)d_in[21];
    const float* c1b = (const float*)d_in[22];
    const float* c2w = (const float*)d_in[23];
    const float* c2b = (const float*)d_in[24];
    const float* f1w = (const float*)d_in[25];
    const float* f1b = (const float*)d_in[26];
    const float* f2w = (const float*)d_in[27];
    const float* f2b = (const float*)d_in[28];

    float* ws = (float*)d_ws;
    float* A  = ws;                 // 17,334,272 floats
    float* Bb = ws + 17334272;      // 17,334,272 floats
    float* Cc = ws + 34668544;      // 34,668,544 floats
    float* out = (float*)d_out;

    dim3 blk(256);
    size_t sm23 = (size_t)(8 * 25 * 25 + 8 * 144) * sizeof(float);  // 24.6 KB
    size_t sm46 = (size_t)(8 * 14 * 48 + 8 * 144) * sizeof(float);  // 26.1 KB

    // r5a bottleneck
    conv1x1_kernel<<<dim3(5, 16, 64), blk, 0, stream>>>(
        x, w1, rb1, g1, be1, m1, v1, nullptr, A, 1024, 512, 529, F_BN | F_RELU);
    conv3x3_kernel<<<dim3(1, 32, 64), blk, sm23, stream>>>(
        A, w2, rb2, g2, be2, m2, v2, Bb, 512, 512, 23, 23, 23, F_BN | F_RELU);
    conv1x1_kernel<<<dim3(5, 32, 64), blk, 0, stream>>>(
        Bb, w3, rb3, nullptr, nullptr, nullptr, nullptr, x, Cc, 512, 1024, 529, F_RES);
    // b1 / b2 / b3
    conv1x1_kernel<<<dim3(5, 8, 64), blk, 0, stream>>>(
        Cc, b1w, b1b, nullptr, nullptr, nullptr, nullptr, nullptr, A, 1024, 256, 529, 0);
    conv3x3_kernel<<<dim3(1, 8, 64), blk, sm23, stream>>>(
        A, b2w, b2b, nullptr, nullptr, nullptr, nullptr, Bb, 256, 128, 23, 23, 23, 0);
    conv1x1_kernel<<<dim3(5, 8, 64), blk, 0, stream>>>(
        Bb, b3w, b3b, nullptr, nullptr, nullptr, nullptr, nullptr, A, 128, 256, 529, 0);
    // deconvs into cat buffer (Cc): out1 ch[0,63), out2 ch[63,191), out3 ch[191,212)
    deconv_kernel<<<dim3(9, 4, 64), blk, 0, stream>>>(A, c1w, c1b, Cc, 63, 0, 0);
    deconv_kernel<<<dim3(9, 8, 64), blk, 0, stream>>>(A, c2w, c2b, Cc, 128, 63, 1);
    out3_kernel<<<dim3(11109), blk, 0, stream>>>(Cc);
    // f1 / f2
    conv3x3_kernel<<<dim3(4, 8, 64), blk, sm46, stream>>>(
        Cc, f1w, f1b, nullptr, nullptr, nullptr, nullptr, Bb, 212, 128, 46, 46, 12, F_RELU);
    conv1x1_kernel<<<dim3(17, 4, 64), blk, 0, stream>>>(
        Bb, f2w, f2b, nullptr, nullptr, nullptr, nullptr, nullptr, A, 128, 112, 2116, 0);
    // final argmax/gather
    argmax_kernel<<<dim3(28, 64), dim3(64), 0, stream>>>(A, out);
}

// Round 3
// 2559.354 us; speedup vs baseline: 3.7420x; 3.7420x over previous
//
#include <hip/hip_runtime.h>
#include <math.h>

typedef __attribute__((ext_vector_type(8))) _Float16 f16x8;
typedef __attribute__((ext_vector_type(4))) float f32x4;

union HU { _Float16 h; unsigned short u; };

__device__ __forceinline__ void split32(float v, unsigned short& hh, unsigned short& ll) {
    HU a, b;
    a.h = (_Float16)v;
    b.h = (_Float16)(v - (float)a.h);
    hh = a.u; ll = b.u;
}
__device__ __forceinline__ float h2f(unsigned short s) { HU a; a.u = s; return (float)a.h; }

__device__ __forceinline__ void gload16(const unsigned short* g, unsigned short* l) {
    __builtin_amdgcn_global_load_lds(
        (const __attribute__((address_space(1))) unsigned int*)g,
        (__attribute__((address_space(3))) unsigned int*)l, 16, 0, 0);
}

// ---------------------------------------------------------------------------
// Split-fp16 implicit-GEMM conv. Values are (hi+lo) fp16 plane pairs.
// out[px][co] = sum_{t,ci} in[px+shift(t)][ci] * W[co][t][ci]  (3-term MFMA)
// BM=128 px, BN=NFRAG*32 co, BK=32. 256 thr = 4 waves, wave tile 64px x BN/2.
// ---------------------------------------------------------------------------
struct ConvP {
    const unsigned short* in;     // hi plane, NHWC fp16
    const unsigned short* wr;     // hi plane, [COp][T][CIp] fp16
    const float* bias;
    const float* resx;            // fp32 NCHW residual (or null)
    unsigned short* out;          // hi plane
    long long loIn, loW, loOut;   // element offsets hi->lo plane
    int H, W;                     // output spatial dims
    int inWP, inPix0, inImg;      // input geometry (pixel units)
    int CIp, T, wRow, pxTotal;
    int oImg, oPix0, oYstr, oXstr, oC, oChOff, CO;
    int resCstr, resImg, relu;
    int shift[16];
    int woff[16];
};

template<int NFRAG>
__global__ __launch_bounds__(256) void convmm(ConvP p)
{
    __shared__ unsigned short lAh[128 * 32];
    __shared__ unsigned short lAl[128 * 32];
    __shared__ unsigned short lBh[128 * 32];
    __shared__ unsigned short lBl[128 * 32];

    const int tid  = threadIdx.x;
    const int w    = tid >> 6;
    const int lane = tid & 63;
    const int lo   = lane & 15, hi = lane >> 4;
    const int wm   = w >> 1,    wn = w & 1;
    const int HW   = p.H * p.W;

    long long aOff[2];
    const int aoct = lane & 3;
    for (int j = 0; j < 2; ++j) {
        int instr = 2 * w + j;
        int px = blockIdx.x * 128 + instr * 16 + (lane >> 2);
        if (px >= p.pxTotal) px = p.pxTotal - 1;
        int n = px / HW, pr = px - n * HW;
        int y = pr / p.W, x = pr - y * p.W;
        aOff[j] = ((long long)n * p.inImg + p.inPix0 + y * p.inWP + x) * (long long)p.CIp
                  + aoct * 8;
    }
    constexpr int NB = NFRAG / 2;
    long long bOff[NB];
    const int cob = blockIdx.y * (NFRAG * 32);
    for (int j = 0; j < NB; ++j) {
        int instr = NB * w + j;
        int col = instr * 16 + (lane >> 2);
        bOff[j] = (long long)(cob + col) * p.wRow + aoct * 8;
    }

    f32x4 acc[4][NFRAG];
#pragma unroll
    for (int q = 0; q < 4; ++q)
#pragma unroll
        for (int r = 0; r < NFRAG; ++r) acc[q][r] = (f32x4){0.f, 0.f, 0.f, 0.f};

    for (int t = 0; t < p.T; ++t) {
        const long long tShift = (long long)p.shift[t] * p.CIp;
        const int wo = p.woff[t];
        for (int ci0 = 0; ci0 < p.CIp; ci0 += 32) {
            __syncthreads();
#pragma unroll
            for (int j = 0; j < 2; ++j) {
                gload16(p.in + aOff[j] + tShift + ci0,          &lAh[(2 * w + j) * 512]);
                gload16(p.in + p.loIn + aOff[j] + tShift + ci0, &lAl[(2 * w + j) * 512]);
            }
#pragma unroll
            for (int j = 0; j < NB; ++j) {
                gload16(p.wr + bOff[j] + wo + ci0,         &lBh[(NB * w + j) * 512]);
                gload16(p.wr + p.loW + bOff[j] + wo + ci0, &lBl[(NB * w + j) * 512]);
            }
            __syncthreads();

            f16x8 aFh[4], aFl[4], bFh[NFRAG], bFl[NFRAG];
#pragma unroll
            for (int q = 0; q < 4; ++q) {
                int idx = (wm * 64 + q * 16 + lo) * 32 + hi * 8;
                aFh[q] = *(const f16x8*)&lAh[idx];
                aFl[q] = *(const f16x8*)&lAl[idx];
            }
#pragma unroll
            for (int r = 0; r < NFRAG; ++r) {
                int idx = (wn * NFRAG * 16 + r * 16 + lo) * 32 + hi * 8;
                bFh[r] = *(const f16x8*)&lBh[idx];
                bFl[r] = *(const f16x8*)&lBl[idx];
            }
            // 3-term split product: hh, hl, lh (ll dropped, ~2^-22 rel)
#pragma unroll
            for (int q = 0; q < 4; ++q)
#pragma unroll
                for (int r = 0; r < NFRAG; ++r)
                    acc[q][r] = __builtin_amdgcn_mfma_f32_16x16x32_f16(
                        aFh[q], bFh[r], acc[q][r], 0, 0, 0);
#pragma unroll
            for (int q = 0; q < 4; ++q)
#pragma unroll
                for (int r = 0; r < NFRAG; ++r)
                    acc[q][r] = __builtin_amdgcn_mfma_f32_16x16x32_f16(
                        aFh[q], bFl[r], acc[q][r], 0, 0, 0);
#pragma unroll
            for (int q = 0; q < 4; ++q)
#pragma unroll
                for (int r = 0; r < NFRAG; ++r)
                    acc[q][r] = __builtin_amdgcn_mfma_f32_16x16x32_f16(
                        aFl[q], bFh[r], acc[q][r], 0, 0, 0);
        }
    }

    const int coB = cob + wn * NFRAG * 16;
#pragma unroll
    for (int q = 0; q < 4; ++q) {
        int pxBase = blockIdx.x * 128 + wm * 64 + q * 16 + hi * 4;
#pragma unroll
        for (int r4 = 0; r4 < 4; ++r4) {
            int px = pxBase + r4;
            if (px >= p.pxTotal) continue;
            int n = px / HW, pr = px - n * HW;
            int y = pr / p.W, x = pr - y * p.W;
            long long obase = ((long long)n * p.oImg + p.oPix0 + y * p.oYstr + x * p.oXstr)
                              * (long long)p.oC + p.oChOff;
#pragma unroll
            for (int nf = 0; nf < NFRAG; ++nf) {
                int co = coB + nf * 16 + lo;
                if (co < p.CO) {
                    float v = acc[q][nf][r4] + p.bias[co];
                    if (p.resx)
                        v += p.resx[(long long)n * p.resImg + (long long)co * p.resCstr + pr];
                    if (p.relu) v = fmaxf(v, 0.f);
                    unsigned short vh, vl;
                    split32(v, vh, vl);
                    p.out[obase + co] = vh;
                    p.out[p.loOut + obase + co] = vl;
                }
            }
        }
    }
}

// ---------------------------------------------------------------------------
// x fp32 NCHW (64,1024,23,23) -> unpadded NHWC hi/lo fp16 [64][529][1024]
// ---------------------------------------------------------------------------
__global__ __launch_bounds__(256) void prep_x(const float* __restrict__ in,
                                              unsigned short* __restrict__ xp,
                                              long long loOff)
{
    __shared__ float t[64][65];
    const int n = blockIdx.z, c0 = blockIdx.y * 64, px0 = blockIdx.x * 64;
    const int tid = threadIdx.x;
    const int colA = tid & 63, rowA = tid >> 6;
#pragma unroll
    for (int i = 0; i < 16; ++i) {
        int cl = i * 4 + rowA;
        int px = px0 + colA;
        float v = 0.f;
        if (px < 529) v = in[((size_t)n * 1024 + c0 + cl) * 529 + px];
        t[cl][colA] = v;
    }
    __syncthreads();
#pragma unroll
    for (int i = 0; i < 16; ++i) {
        int pxl = i * 4 + rowA;
        int px = px0 + pxl;
        if (px < 529) {
            unsigned short vh, vl;
            split32(t[colA][pxl], vh, vl);
            long long o = ((long long)n * 529 + px) * 1024 + c0 + colA;
            xp[o] = vh; xp[o + loOff] = vl;
        }
    }
}

// weights OIHW fp32 -> [COp][T][CIp] hi/lo fp16 (optional per-co scale fold)
__global__ __launch_bounds__(256) void prep_w(const float* __restrict__ src,
                                              unsigned short* __restrict__ dst, long long loW,
                                              int CO, int CI, int T, int COp, int CIp,
                                              const float* __restrict__ scale)
{
    long long idx = (long long)blockIdx.x * 256 + threadIdx.x;
    long long tot = (long long)COp * T * CIp;
    if (idx >= tot) return;
    int ci = idx % CIp; long long r = idx / CIp;
    int t = r % T; int co = r / T;
    float v = 0.f;
    if (co < CO && ci < CI) {
        v = src[((long long)co * CI + ci) * T + t];
        if (scale) v *= scale[co];
    }
    unsigned short vh, vl;
    split32(v, vh, vl);
    dst[idx] = vh; dst[idx + loW] = vl;
}

// deconv weights (256, CO, 4, 4) fp32 -> [128][16][256] hi/lo (flip+transpose)
__global__ __launch_bounds__(256) void prep_w_deconv(const float* __restrict__ src,
                                                     unsigned short* __restrict__ dst,
                                                     long long loW, int CO)
{
    int idx = blockIdx.x * 256 + threadIdx.x;
    if (idx >= 128 * 16 * 256) return;
    int ci = idx & 255; int r = idx >> 8;
    int tap = r & 15; int co = r >> 4;
    int ky = tap >> 2, kx = tap & 3;
    float v = 0.f;
    if (co < CO) v = src[((size_t)ci * CO + co) * 16 + (3 - ky) * 4 + (3 - kx)];
    unsigned short vh, vl;
    split32(v, vh, vl);
    dst[idx] = vh; dst[idx + loW] = vl;
}

__global__ __launch_bounds__(512) void prep_sb(
    const float* g1, const float* be1, const float* m1, const float* v1, const float* b1,
    const float* g2, const float* be2, const float* m2, const float* v2, const float* b2,
    float* s1, float* bb1, float* s2, float* bb2)
{
    int i = threadIdx.x;
    float s = g1[i] * rsqrtf(v1[i] + 1e-5f);
    s1[i] = s; bb1[i] = (b1[i] - m1[i]) * s + be1[i];
    s = g2[i] * rsqrtf(v2[i] + 1e-5f);
    s2[i] = s; bb2[i] = (b2[i] - m2[i]) * s + be2[i];
}

// zero the 1-px border ring of a padded NHWC plane
__global__ __launch_bounds__(256) void zero_border(unsigned short* buf,
                                                   int HP, int WP, int C, int nb)
{
    long long idx = (long long)blockIdx.x * 256 + threadIdx.x;
    long long tot = (long long)64 * nb * C;
    if (idx >= tot) return;
    int c = idx % C; long long r = idx / C;
    int b = r % nb; int n = r / nb;
    int pp;
    if (b < WP) pp = b;
    else if (b < 2 * WP) pp = (HP - 1) * WP + (b - WP);
    else { int q = b - 2 * WP; int row = 1 + (q >> 1); pp = row * WP + ((q & 1) ? (WP - 1) : 0); }
    buf[((long long)n * HP * WP + pp) * C + c] = 0;
}

// zero channels [212,224) of one cat plane for all pixels
__global__ __launch_bounds__(256) void zero_chpad(unsigned short* cat)
{
    long long idx = (long long)blockIdx.x * 256 + threadIdx.x;
    if (idx >= (long long)64 * 2304 * 12) return;
    int c = 212 + (int)(idx % 12);
    long long pp = idx / 12;
    cat[pp * 224 + c] = 0;
}

// out3 = sqrt(o1[3j]^2+o1[3j+1]^2+o1[3j+2]^2) -> cat ch 191+j (interior)
__global__ __launch_bounds__(256) void out3_k(unsigned short* cat, long long loOff)
{
    long long idx = (long long)blockIdx.x * 256 + threadIdx.x;
    if (idx >= (long long)64 * 2116 * 21) return;
    int j = idx % 21; long long r = idx / 21;
    int pr = r % 2116; int n = r / 2116;
    int y = pr / 46, x = pr - y * 46;
    long long base = ((long long)n * 2304 + (y + 1) * 48 + (x + 1)) * 224;
    float a = h2f(cat[base + 3 * j])     + h2f(cat[base + 3 * j + loOff]);
    float b = h2f(cat[base + 3 * j + 1]) + h2f(cat[base + 3 * j + 1 + loOff]);
    float c = h2f(cat[base + 3 * j + 2]) + h2f(cat[base + 3 * j + 2 + loOff]);
    unsigned short vh, vl;
    split32(sqrtf(a * a + b * b + c * c), vh, vl);
    cat[base + 191 + j] = vh;
    cat[base + 191 + j + loOff] = vl;
}

// ---------------------------------------------------------------------------
// argmax/gather on f2 out (NHWC hi/lo, C=112). flat = q*59248+a*1288+b*28+k
// ---------------------------------------------------------------------------
__global__ __launch_bounds__(64) void argmax_hl(const unsigned short* __restrict__ h,
                                                long long loOff, float* __restrict__ outp)
{
    const int k = blockIdx.x, n = blockIdx.y, t = threadIdx.x;
    const unsigned short* b = h + (size_t)n * 2116 * 112;
    float best = -INFINITY; int ba = 0; int bb = t;
    if (t < 46) {
        for (int a = 0; a < 46; ++a) {
            int f = a * 1288 + t * 28 + k;          // q = 0 (heatmap)
            int c = f / 2116, pr = f - c * 2116;
            long long e = (long long)pr * 112 + c;
            float v = h2f(b[e]) + h2f(b[e + loOff]);
            if (v > best) { best = v; ba = a; }     // strict > = first index
        }
    }
#pragma unroll
    for (int off = 32; off > 0; off >>= 1) {
        float ov = __shfl_down(best, off);
        int oa = __shfl_down(ba, off), ob = __shfl_down(bb, off);
        if (ov > best || (ov == best && ob < bb)) { best = ov; ba = oa; bb = ob; }
    }
    if (t == 0) {
        for (int q = 1; q <= 3; ++q) {
            int f = q * 59248 + ba * 1288 + bb * 28 + k;
            int c = f / 2116, pr = f - c * 2116;
            long long e = (long long)pr * 112 + c;
            outp[(size_t)n * 84 + k * 3 + (q - 1)] = h2f(b[e]) + h2f(b[e + loOff]);
        }
    }
}

// ---------------------------------------------------------------------------
extern "C" void kernel_launch(void* const* d_in, const int* in_sizes, int n_in,
                              void* d_out, int out_size, void* d_ws, size_t ws_size,
                              hipStream_t stream)
{
    const float* x   = (const float*)d_in[0];
    const float* w1  = (const float*)d_in[1];
    const float* rb1 = (const float*)d_in[2];
    const float* g1  = (const float*)d_in[3];
    const float* be1 = (const float*)d_in[4];
    const float* m1  = (const float*)d_in[5];
    const float* v1  = (const float*)d_in[6];
    const float* w2  = (const float*)d_in[7];
    const float* rb2 = (const float*)d_in[8];
    const float* g2  = (const float*)d_in[9];
    const float* be2 = (const float*)d_in[10];
    const float* m2  = (const float*)d_in[11];
    const float* v2  = (const float*)d_in[12];
    const float* w3  = (const float*)d_in[13];
    const float* rb3 = (const float*)d_in[14];
    const float* b1w = (const float*)d_in[15];
    const float* b1b = (const float*)d_in[16];
    const float* b2w = (const float*)d_in[17];
    const float* b2b = (const float*)d_in[18];
    const float* b3w = (const float*)d_in[19];
    const float* b3b = (const float*)d_in[20];
    const float* c1w = (const float*)d_in[21];
    const float* c1b = (const float*)d_in[22];
    const float* c2w = (const float*)d_in[23];
    const float* c2b = (const float*)d_in[24];
    const float* f1w = (const float*)d_in[25];
    const float* f1b = (const float*)d_in[26];
    const float* f2w = (const float*)d_in[27];
    const float* f2b = (const float*)d_in[28];

    unsigned short* wsb = (unsigned short*)d_ws;
    // ---- weight arena [0, 24MiB) ---- (element = unsigned short)
    size_t woffE = 0;
    auto walloc = [&](size_t planeElems) {
        unsigned short* p = wsb + woffE; woffE += 2 * planeElems; return p;
    };
    unsigned short* Wr1  = walloc(524288);    // 512*1024
    unsigned short* Wr2  = walloc(2359296);   // 512*9*512
    unsigned short* Wr3  = walloc(524288);    // 1024*512
    unsigned short* Wr4  = walloc(262144);    // 256*1024
    unsigned short* Wr5  = walloc(294912);    // 128*9*256
    unsigned short* Wr6  = walloc(32768);     // 256*128
    unsigned short* Wr7  = walloc(524288);    // 128*16*256
    unsigned short* Wr8  = walloc(524288);
    unsigned short* Wr9  = walloc(258048);    // 128*9*224
    unsigned short* Wr10 = walloc(16384);     // 128*128
    char* fscr = (char*)d_ws + 23068672;      // fp32 scratch @22MiB
    float* s1  = (float*)(fscr);
    float* bb1 = (float*)(fscr + 2048);
    float* s2  = (float*)(fscr + 4096);
    float* bb2 = (float*)(fscr + 6144);

    // ---- activation arena (element offsets = byte/2), overlap-verified ----
    unsigned short* XPU = wsb + 12582912;   // [24.0M, 162.7M) bytes
    unsigned short* R1  = wsb + 81920000;   // [163.8M, 245.8M)
    unsigned short* R2  = wsb + 12582912;   // [24.0M, 93.3M)   (over XPU, dead)
    unsigned short* R3  = wsb + 47251456;   // [94.5M, 233.2M)
    unsigned short* B1  = wsb + 116588544;  // [233.2M, 274.1M)
    unsigned short* B2  = wsb + 12582912;   // [24.0M, 41.3M)
    unsigned short* B3  = wsb + 21250048;   // [42.5M, 83.5M)
    unsigned short* CAT = wsb + 47251456;   // [94.5M, 226.6M)  (over R3, dead)
    unsigned short* F1  = wsb + 12582912;   // [24.0M, 93.3M)
    unsigned short* F2  = wsb + 47251456;   // [94.5M, 155.2M)  (over CAT, dead)
    const long long XPU_L = 34668544, R1_L = 20480000, R2_L = 17334272, R3_L = 34668544;
    const long long B1_L = 10240000, B2_L = 4333568, B3_L = 10240000;
    const long long CAT_L = 33030144, F1_L = 17334272, F2_L = 15167488;

    // ---- prep ----
    prep_sb<<<1, 512, 0, stream>>>(g1, be1, m1, v1, rb1, g2, be2, m2, v2, rb2, s1, bb1, s2, bb2);
    auto pw = [&](const float* src, unsigned short* dst, long long loW, int CO, int CI,
                  int T, int COp, int CIp, const float* sc) {
        long long tot = (long long)COp * T * CIp;
        prep_w<<<(tot + 255) / 256, 256, 0, stream>>>(src, dst, loW, CO, CI, T, COp, CIp, sc);
    };
    pw(w1,  Wr1, 524288,  512, 1024, 1, 512, 1024, s1);
    pw(w2,  Wr2, 2359296, 512, 512,  9, 512, 512,  s2);
    pw(w3,  Wr3, 524288,  1024, 512, 1, 1024, 512, nullptr);
    pw(b1w, Wr4, 262144,  256, 1024, 1, 256, 1024, nullptr);
    pw(b2w, Wr5, 294912,  128, 256,  9, 128, 256,  nullptr);
    pw(b3w, Wr6, 32768,   256, 128,  1, 256, 128,  nullptr);
    prep_w_deconv<<<(128 * 16 * 256) / 256, 256, 0, stream>>>(c1w, Wr7, 524288, 63);
    prep_w_deconv<<<(128 * 16 * 256) / 256, 256, 0, stream>>>(c2w, Wr8, 524288, 128);
    pw(f1w, Wr9, 258048,  128, 212,  9, 128, 224,  nullptr);
    pw(f2w, Wr10, 16384,  112, 128,  1, 128, 128,  nullptr);
    prep_x<<<dim3(9, 16, 64), 256, 0, stream>>>(x, XPU, XPU_L);

    auto zb = [&](unsigned short* buf, long long loOff, int HP, int WP, int C) {
        int nb = 2 * WP + 2 * (HP - 2);
        long long tot = (long long)64 * nb * C;
        zero_border<<<(tot + 255) / 256, 256, 0, stream>>>(buf, HP, WP, C, nb);
        zero_border<<<(tot + 255) / 256, 256, 0, stream>>>(buf + loOff, HP, WP, C, nb);
    };

    auto conv = [&](int NFRAG, const unsigned short* in, long long loIn,
                    const unsigned short* wr, long long loW,
                    const float* bias, const float* resx, unsigned short* outp, long long loOut,
                    int H, int W, int inWP, int inPix0, int inImg, int CIp, int T, int wRow,
                    int oImg, int oPix0, int oYstr, int oXstr, int oC, int oChOff, int CO,
                    int relu, const int* shifts, const int* woffs) {
        ConvP p{};
        p.in = in; p.wr = wr; p.bias = bias; p.resx = resx; p.out = outp;
        p.loIn = loIn; p.loW = loW; p.loOut = loOut;
        p.H = H; p.W = W; p.inWP = inWP; p.inPix0 = inPix0; p.inImg = inImg;
        p.CIp = CIp; p.T = T; p.wRow = wRow; p.pxTotal = 64 * H * W;
        p.oImg = oImg; p.oPix0 = oPix0; p.oYstr = oYstr; p.oXstr = oXstr;
        p.oC = oC; p.oChOff = oChOff; p.CO = CO;
        p.resCstr = 529; p.resImg = 541696; p.relu = relu;
        for (int t = 0; t < T; ++t) { p.shift[t] = shifts[t]; p.woff[t] = woffs[t]; }
        int BN = NFRAG * 32;
        dim3 grid((p.pxTotal + 127) / 128, (CO + BN - 1) / BN);
        if (NFRAG == 4) convmm<4><<<grid, 256, 0, stream>>>(p);
        else            convmm<2><<<grid, 256, 0, stream>>>(p);
    };

    int z16[16] = {0};
    int sh9_25[16], wo9_512[16], wo9_256[16], sh9_48[16], wo9_224[16];
    for (int t = 0; t < 9; ++t) {
        int ky = t / 3, kx = t % 3;
        sh9_25[t] = (ky - 1) * 25 + (kx - 1);
        sh9_48[t] = (ky - 1) * 48 + (kx - 1);
        wo9_512[t] = t * 512; wo9_256[t] = t * 256; wo9_224[t] = t * 224;
    }

    // r5a bottleneck
    zb(R1, R1_L, 25, 25, 512);
    conv(4, XPU, XPU_L, Wr1, 524288, bb1, nullptr, R1, R1_L,
         23, 23, 23, 0, 529, 1024, 1, 1024, 625, 26, 25, 1, 512, 0, 512, 1, z16, z16);
    conv(4, R1, R1_L, Wr2, 2359296, bb2, nullptr, R2, R2_L,
         23, 23, 25, 26, 625, 512, 9, 9 * 512, 529, 0, 23, 1, 512, 0, 512, 1, sh9_25, wo9_512);
    zb(B1, B1_L, 25, 25, 256);                       // after conv2 (over R1 tail)
    conv(4, R2, R2_L, Wr3, 524288, rb3, x, R3, R3_L,
         23, 23, 23, 0, 529, 512, 1, 512, 529, 0, 23, 1, 1024, 0, 1024, 0, z16, z16);
    zb(B3, B3_L, 25, 25, 256);                       // after conv3 (over R2 region)
    conv(4, R3, R3_L, Wr4, 262144, b1b, nullptr, B1, B1_L,
         23, 23, 23, 0, 529, 1024, 1, 1024, 625, 26, 25, 1, 256, 0, 256, 0, z16, z16);
    zb(CAT, CAT_L, 48, 48, 224);                     // after b1 (over R3 region)
    {
        long long tot = (long long)64 * 2304 * 12;
        zero_chpad<<<(tot + 255) / 256, 256, 0, stream>>>(CAT);
        zero_chpad<<<(tot + 255) / 256, 256, 0, stream>>>(CAT + CAT_L);
    }
    conv(4, B1, B1_L, Wr5, 294912, b2b, nullptr, B2, B2_L,
         23, 23, 25, 26, 625, 256, 9, 9 * 256, 529, 0, 23, 1, 128, 0, 128, 0, sh9_25, wo9_256);
    conv(4, B2, B2_L, Wr6, 32768, b3b, nullptr, B3, B3_L,
         23, 23, 23, 0, 529, 128, 1, 128, 625, 26, 25, 1, 256, 0, 256, 0, z16, z16);

    // deconvs: 4 parity classes each, B3 -> CAT (48x48 padded, C=224)
    for (int a = 0; a < 2; ++a)
        for (int b = 0; b < 2; ++b) {
            int sh[16], wo[16];
            for (int ty = 0; ty < 2; ++ty)
                for (int tx = 0; tx < 2; ++tx) {
                    int tI = ty * 2 + tx;
                    sh[tI] = (a + ty - 1) * 25 + (b + tx - 1);
                    wo[tI] = ((a + 2 * ty) * 4 + (b + 2 * tx)) * 256;
                }
            int oPix0 = (a + 1) * 48 + (b + 1);
            conv(2, B3, B3_L, Wr7, 524288, c1b, nullptr, CAT, CAT_L,
                 23, 23, 25, 26, 625, 256, 4, 16 * 256, 2304, oPix0, 96, 2, 224, 0, 63,
                 0, sh, wo);
            conv(4, B3, B3_L, Wr8, 524288, c2b, nullptr, CAT, CAT_L,
                 23, 23, 25, 26, 625, 256, 4, 16 * 256, 2304, oPix0, 96, 2, 224, 63, 128,
                 1, sh, wo);
        }
    {
        long long tot = (long long)64 * 2116 * 21;
        out3_k<<<(tot + 255) / 256, 256, 0, stream>>>(CAT, CAT_L);
    }

    // f1 / f2
    conv(4, CAT, CAT_L, Wr9, 258048, f1b, nullptr, F1, F1_L,
         46, 46, 48, 49, 2304, 224, 9, 9 * 224, 2116, 0, 46, 1, 128, 0, 128, 1,
         sh9_48, wo9_224);
    conv(2, F1, F1_L, Wr10, 16384, f2b, nullptr, F2, F2_L,
         46, 46, 46, 0, 2116, 128, 1, 128, 2116, 0, 46, 1, 112, 0, 112, 0, z16, z16);

    argmax_hl<<<dim3(28, 64), dim3(64), 0, stream>>>(F2, F2_L, (float*)d_out);
}

// Round 4
// 2350.342 us; speedup vs baseline: 4.0748x; 1.0889x over previous
//
#include <hip/hip_runtime.h>
#include <math.h>

typedef __attribute__((ext_vector_type(8))) _Float16 f16x8;
typedef __attribute__((ext_vector_type(4))) float f32x4;

union HU { _Float16 h; unsigned short u; };

__device__ __forceinline__ void split32(float v, unsigned short& hh, unsigned short& ll) {
    HU a, b;
    a.h = (_Float16)v;
    b.h = (_Float16)(v - (float)a.h);
    hh = a.u; ll = b.u;
}
__device__ __forceinline__ float h2f(unsigned short s) { HU a; a.u = s; return (float)a.h; }

__device__ __forceinline__ void gload16(const unsigned short* g, unsigned short* l) {
    __builtin_amdgcn_global_load_lds(
        (const __attribute__((address_space(1))) unsigned int*)g,
        (__attribute__((address_space(3))) unsigned int*)l, 16, 0, 0);
}

// ---------------------------------------------------------------------------
// Old-style split-fp16 implicit-GEMM (kept for 1x1 convs: T=1, linear px).
// ---------------------------------------------------------------------------
struct ConvP {
    const unsigned short* in;
    const unsigned short* wr;
    const float* bias;
    const float* resx;            // fp32 NCHW residual (or null)
    unsigned short* out;
    long long loIn, loW, loOut;
    int H, W;
    int inWP, inPix0, inImg;
    int CIp, T, wRow, pxTotal;
    int oImg, oPix0, oYstr, oXstr, oC, oChOff, CO;
    int resCstr, resImg, relu;
    int shift[16];
    int woff[16];
};

template<int NFRAG>
__global__ __launch_bounds__(256) void convmm(ConvP p)
{
    __shared__ unsigned short lAh[128 * 32];
    __shared__ unsigned short lAl[128 * 32];
    __shared__ unsigned short lBh[128 * 32];
    __shared__ unsigned short lBl[128 * 32];

    const int tid  = threadIdx.x;
    const int w    = tid >> 6;
    const int lane = tid & 63;
    const int lo   = lane & 15, hi = lane >> 4;
    const int wm   = w >> 1,    wn = w & 1;
    const int HW   = p.H * p.W;

    long long aOff[2];
    const int aoct = lane & 3;
    for (int j = 0; j < 2; ++j) {
        int instr = 2 * w + j;
        int px = blockIdx.x * 128 + instr * 16 + (lane >> 2);
        if (px >= p.pxTotal) px = p.pxTotal - 1;
        int n = px / HW, pr = px - n * HW;
        int y = pr / p.W, x = pr - y * p.W;
        aOff[j] = ((long long)n * p.inImg + p.inPix0 + y * p.inWP + x) * (long long)p.CIp
                  + aoct * 8;
    }
    constexpr int NB = NFRAG / 2;
    long long bOff[NB];
    const int cob = blockIdx.y * (NFRAG * 32);
    for (int j = 0; j < NB; ++j) {
        int instr = NB * w + j;
        int col = instr * 16 + (lane >> 2);
        bOff[j] = (long long)(cob + col) * p.wRow + aoct * 8;
    }

    f32x4 acc[4][NFRAG];
#pragma unroll
    for (int q = 0; q < 4; ++q)
#pragma unroll
        for (int r = 0; r < NFRAG; ++r) acc[q][r] = (f32x4){0.f, 0.f, 0.f, 0.f};

    for (int t = 0; t < p.T; ++t) {
        const long long tShift = (long long)p.shift[t] * p.CIp;
        const int wo = p.woff[t];
        for (int ci0 = 0; ci0 < p.CIp; ci0 += 32) {
            __syncthreads();
#pragma unroll
            for (int j = 0; j < 2; ++j) {
                gload16(p.in + aOff[j] + tShift + ci0,          &lAh[(2 * w + j) * 512]);
                gload16(p.in + p.loIn + aOff[j] + tShift + ci0, &lAl[(2 * w + j) * 512]);
            }
#pragma unroll
            for (int j = 0; j < NB; ++j) {
                gload16(p.wr + bOff[j] + wo + ci0,         &lBh[(NB * w + j) * 512]);
                gload16(p.wr + p.loW + bOff[j] + wo + ci0, &lBl[(NB * w + j) * 512]);
            }
            __syncthreads();

            f16x8 aFh[4], aFl[4], bFh[NFRAG], bFl[NFRAG];
#pragma unroll
            for (int q = 0; q < 4; ++q) {
                int idx = (wm * 64 + q * 16 + lo) * 32 + hi * 8;
                aFh[q] = *(const f16x8*)&lAh[idx];
                aFl[q] = *(const f16x8*)&lAl[idx];
            }
#pragma unroll
            for (int r = 0; r < NFRAG; ++r) {
                int idx = (wn * NFRAG * 16 + r * 16 + lo) * 32 + hi * 8;
                bFh[r] = *(const f16x8*)&lBh[idx];
                bFl[r] = *(const f16x8*)&lBl[idx];
            }
#pragma unroll
            for (int q = 0; q < 4; ++q)
#pragma unroll
                for (int r = 0; r < NFRAG; ++r)
                    acc[q][r] = __builtin_amdgcn_mfma_f32_16x16x32_f16(
                        aFh[q], bFh[r], acc[q][r], 0, 0, 0);
#pragma unroll
            for (int q = 0; q < 4; ++q)
#pragma unroll
                for (int r = 0; r < NFRAG; ++r)
                    acc[q][r] = __builtin_amdgcn_mfma_f32_16x16x32_f16(
                        aFh[q], bFl[r], acc[q][r], 0, 0, 0);
#pragma unroll
            for (int q = 0; q < 4; ++q)
#pragma unroll
                for (int r = 0; r < NFRAG; ++r)
                    acc[q][r] = __builtin_amdgcn_mfma_f32_16x16x32_f16(
                        aFl[q], bFh[r], acc[q][r], 0, 0, 0);
        }
    }

    const int coB = cob + wn * NFRAG * 16;
#pragma unroll
    for (int q = 0; q < 4; ++q) {
        int pxBase = blockIdx.x * 128 + wm * 64 + q * 16 + hi * 4;
#pragma unroll
        for (int r4 = 0; r4 < 4; ++r4) {
            int px = pxBase + r4;
            if (px >= p.pxTotal) continue;
            int n = px / HW, pr = px - n * HW;
            int y = pr / p.W, x = pr - y * p.W;
            long long obase = ((long long)n * p.oImg + p.oPix0 + y * p.oYstr + x * p.oXstr)
                              * (long long)p.oC + p.oChOff;
#pragma unroll
            for (int nf = 0; nf < NFRAG; ++nf) {
                int co = coB + nf * 16 + lo;
                if (co < p.CO) {
                    float v = acc[q][nf][r4] + p.bias[co];
                    if (p.resx)
                        v += p.resx[(long long)n * p.resImg + (long long)co * p.resCstr + pr];
                    if (p.relu) v = fmaxf(v, 0.f);
                    unsigned short vh, vl;
                    split32(v, vh, vl);
                    p.out[obase + co] = vh;
                    p.out[p.loOut + obase + co] = vl;
                }
            }
        }
    }
}

// ---------------------------------------------------------------------------
// Halo-staged split-fp16 conv for 3x3 / deconv-taps / f1.
// ci-outer, tap-inner: A staged once per 32-ci chunk into a 256-px halo'd LDS
// window (all taps read shifted fragments from LDS). B double-buffered across
// taps (1 barrier/tap). Per-image(-pair) blocking keeps the window contiguous
// in the padded layout. Bijective XCD swizzle, co-major logical order.
// ---------------------------------------------------------------------------
struct HConvP {
    const unsigned short* in;     // hi plane, padded NHWC fp16
    const unsigned short* wr;     // hi plane, [COp][T][CIp]
    const float* bias;
    unsigned short* out;
    long long loIn, loW, loOut;
    int W, IMG_PX, UNIT, UNIT_PX, BPI, nUnits;
    int inWP, inPix0, inImg, halo;
    int CIp, T, wRow;
    int oImg, oPix0, oYstr, oXstr, oC, oChOff, CO;
    int relu;
    int shift[16];                // padded-pixel delta per tap
    int woff[16];                 // weight element offset per tap
};

template<int NFRAG>
__global__ __launch_bounds__(256) void convhalo(HConvP p)
{
    __shared__ unsigned short sA[2 * 8192];   // [hi|lo][256 px][32 ci]
    __shared__ unsigned short sB[2][8192];    // [buf][hi|lo][128 co][32 ci]

    const int tid  = threadIdx.x;
    const int w    = tid >> 6;
    const int lane = tid & 63;
    const int lo   = lane & 15, hi = lane >> 4;
    const int hi8  = hi * 8;
    const int wm   = w >> 1,    wn = w & 1;

    // bijective XCD swizzle (m204): contiguous logical chunks per XCD
    const int nwg = gridDim.x, orig = blockIdx.x;
    const int q8 = nwg >> 3, r8 = nwg & 7;
    const int xcd = orig & 7, lcl = orig >> 3;
    const int l = (xcd < r8 ? xcd * (q8 + 1) : r8 * (q8 + 1) + (xcd - r8) * q8) + lcl;
    const int upb = p.nUnits * p.BPI;
    const int co_blk = l / upb;
    const int rest = l - co_blk * upb;
    const int unit = rest / p.BPI;
    const int b = rest - unit * p.BPI;
    const int cob = co_blk * (NFRAG * 32);

    const int px0 = b * 128;
    const int n0 = unit * p.UNIT + px0 / p.IMG_PX;
    const int pr0 = px0 % p.IMG_PX;
    const long long stageBase = (long long)n0 * p.inImg + p.inPix0
                                + (pr0 / p.W) * p.inWP + (pr0 % p.W) - p.halo;

    int lpx[4];
#pragma unroll
    for (int q = 0; q < 4; ++q) {
        int pl = px0 + wm * 64 + q * 16 + lo;
        if (pl >= p.UNIT_PX) pl = p.UNIT_PX - 1;
        int nn = unit * p.UNIT + pl / p.IMG_PX;
        int pr = pl % p.IMG_PX;
        long long pp = (long long)nn * p.inImg + p.inPix0
                       + (pr / p.W) * p.inWP + (pr % p.W);
        lpx[q] = (int)(pp - stageBase);
    }

    const unsigned short* srcA = p.in + (stageBase + (lane >> 2)) * (long long)p.CIp
                                 + (lane & 3) * 8;

    auto stageA = [&](int ci0) {
#pragma unroll
        for (int j = w; j < 16; j += 4) {
            long long o = (long long)j * 16 * p.CIp + ci0;
            gload16(srcA + o,          &sA[j * 512]);
            gload16(srcA + o + p.loIn, &sA[8192 + j * 512]);
        }
    };
    auto stageB = [&](int buf, int t, int ci0) {
        long long wb = (long long)p.woff[t] + ci0 + (lane & 3) * 8;
#pragma unroll
        for (int j = w; j < 2 * NFRAG; j += 4) {
            long long o = (long long)(cob + j * 16 + (lane >> 2)) * p.wRow + wb;
            gload16(p.wr + o,         &sB[buf][j * 512]);
            gload16(p.wr + o + p.loW, &sB[buf][4096 + j * 512]);
        }
    };

    f32x4 acc[4][NFRAG];
#pragma unroll
    for (int q = 0; q < 4; ++q)
#pragma unroll
        for (int r = 0; r < NFRAG; ++r) acc[q][r] = (f32x4){0.f, 0.f, 0.f, 0.f};

    stageA(0);
    stageB(0, 0, 0);
    __syncthreads();
    int cur = 0;

    for (int ci0 = 0;;) {
        for (int t = 0; t < p.T; ++t) {
            const int sh = p.shift[t];
            f16x8 aFh[4], aFl[4], bFh[NFRAG], bFl[NFRAG];
#pragma unroll
            for (int q = 0; q < 4; ++q) {
                int e = (lpx[q] + sh) * 32 + hi8;
                aFh[q] = *(const f16x8*)&sA[e];
                aFl[q] = *(const f16x8*)&sA[8192 + e];
            }
#pragma unroll
            for (int r = 0; r < NFRAG; ++r) {
                int e = (wn * NFRAG * 16 + r * 16 + lo) * 32 + hi8;
                bFh[r] = *(const f16x8*)&sB[cur][e];
                bFl[r] = *(const f16x8*)&sB[cur][4096 + e];
            }
            if (t + 1 < p.T) stageB(cur ^ 1, t + 1, ci0);
#pragma unroll
            for (int q = 0; q < 4; ++q)
#pragma unroll
                for (int r = 0; r < NFRAG; ++r)
                    acc[q][r] = __builtin_amdgcn_mfma_f32_16x16x32_f16(
                        aFh[q], bFh[r], acc[q][r], 0, 0, 0);
#pragma unroll
            for (int q = 0; q < 4; ++q)
#pragma unroll
                for (int r = 0; r < NFRAG; ++r)
                    acc[q][r] = __builtin_amdgcn_mfma_f32_16x16x32_f16(
                        aFh[q], bFl[r], acc[q][r], 0, 0, 0);
#pragma unroll
            for (int q = 0; q < 4; ++q)
#pragma unroll
                for (int r = 0; r < NFRAG; ++r)
                    acc[q][r] = __builtin_amdgcn_mfma_f32_16x16x32_f16(
                        aFl[q], bFh[r], acc[q][r], 0, 0, 0);
            if (t + 1 < p.T) { __syncthreads(); cur ^= 1; }
        }
        ci0 += 32;
        if (ci0 >= p.CIp) break;
        __syncthreads();            // drain last tap's LDS reads
        stageA(ci0);
        stageB(cur ^ 1, 0, ci0);
        __syncthreads();            // staging complete
        cur ^= 1;
    }

    const int coB = cob + wn * NFRAG * 16;
#pragma unroll
    for (int q = 0; q < 4; ++q) {
#pragma unroll
        for (int r4 = 0; r4 < 4; ++r4) {
            int pl = px0 + wm * 64 + q * 16 + hi * 4 + r4;
            if (pl >= p.UNIT_PX) continue;
            int nn = unit * p.UNIT + pl / p.IMG_PX;
            int pr = pl % p.IMG_PX;
            int y = pr / p.W, x = pr - y * p.W;
            long long obase = ((long long)nn * p.oImg + p.oPix0 + y * p.oYstr + x * p.oXstr)
                              * (long long)p.oC + p.oChOff;
#pragma unroll
            for (int nf = 0; nf < NFRAG; ++nf) {
                int co = coB + nf * 16 + lo;
                if (co < p.CO) {
                    float v = acc[q][nf][r4] + p.bias[co];
                    if (p.relu) v = fmaxf(v, 0.f);
                    unsigned short vh, vl;
                    split32(v, vh, vl);
                    p.out[obase + co] = vh;
                    p.out[p.loOut + obase + co] = vl;
                }
            }
        }
    }
}

// ---------------------------------------------------------------------------
// x fp32 NCHW (64,1024,23,23) -> unpadded NHWC hi/lo fp16 [64][529][1024]
// ---------------------------------------------------------------------------
__global__ __launch_bounds__(256) void prep_x(const float* __restrict__ in,
                                              unsigned short* __restrict__ xp,
                                              long long loOff)
{
    __shared__ float t[64][65];
    const int n = blockIdx.z, c0 = blockIdx.y * 64, px0 = blockIdx.x * 64;
    const int tid = threadIdx.x;
    const int colA = tid & 63, rowA = tid >> 6;
#pragma unroll
    for (int i = 0; i < 16; ++i) {
        int cl = i * 4 + rowA;
        int px = px0 + colA;
        float v = 0.f;
        if (px < 529) v = in[((size_t)n * 1024 + c0 + cl) * 529 + px];
        t[cl][colA] = v;
    }
    __syncthreads();
#pragma unroll
    for (int i = 0; i < 16; ++i) {
        int pxl = i * 4 + rowA;
        int px = px0 + pxl;
        if (px < 529) {
            unsigned short vh, vl;
            split32(t[colA][pxl], vh, vl);
            long long o = ((long long)n * 529 + px) * 1024 + c0 + colA;
            xp[o] = vh; xp[o + loOff] = vl;
        }
    }
}

__global__ __launch_bounds__(256) void prep_w(const float* __restrict__ src,
                                              unsigned short* __restrict__ dst, long long loW,
                                              int CO, int CI, int T, int COp, int CIp,
                                              const float* __restrict__ scale)
{
    long long idx = (long long)blockIdx.x * 256 + threadIdx.x;
    long long tot = (long long)COp * T * CIp;
    if (idx >= tot) return;
    int ci = idx % CIp; long long r = idx / CIp;
    int t = r % T; int co = r / T;
    float v = 0.f;
    if (co < CO && ci < CI) {
        v = src[((long long)co * CI + ci) * T + t];
        if (scale) v *= scale[co];
    }
    unsigned short vh, vl;
    split32(v, vh, vl);
    dst[idx] = vh; dst[idx + loW] = vl;
}

__global__ __launch_bounds__(256) void prep_w_deconv(const float* __restrict__ src,
                                                     unsigned short* __restrict__ dst,
                                                     long long loW, int CO)
{
    int idx = blockIdx.x * 256 + threadIdx.x;
    if (idx >= 128 * 16 * 256) return;
    int ci = idx & 255; int r = idx >> 8;
    int tap = r & 15; int co = r >> 4;
    int ky = tap >> 2, kx = tap & 3;
    float v = 0.f;
    if (co < CO) v = src[((size_t)ci * CO + co) * 16 + (3 - ky) * 4 + (3 - kx)];
    unsigned short vh, vl;
    split32(v, vh, vl);
    dst[idx] = vh; dst[idx + loW] = vl;
}

__global__ __launch_bounds__(512) void prep_sb(
    const float* g1, const float* be1, const float* m1, const float* v1, const float* b1,
    const float* g2, const float* be2, const float* m2, const float* v2, const float* b2,
    float* s1, float* bb1, float* s2, float* bb2)
{
    int i = threadIdx.x;
    float s = g1[i] * rsqrtf(v1[i] + 1e-5f);
    s1[i] = s; bb1[i] = (b1[i] - m1[i]) * s + be1[i];
    s = g2[i] * rsqrtf(v2[i] + 1e-5f);
    s2[i] = s; bb2[i] = (b2[i] - m2[i]) * s + be2[i];
}

__global__ __launch_bounds__(256) void zero_border(unsigned short* buf,
                                                   int HP, int WP, int C, int nb)
{
    long long idx = (long long)blockIdx.x * 256 + threadIdx.x;
    long long tot = (long long)64 * nb * C;
    if (idx >= tot) return;
    int c = idx % C; long long r = idx / C;
    int b = r % nb; int n = r / nb;
    int pp;
    if (b < WP) pp = b;
    else if (b < 2 * WP) pp = (HP - 1) * WP + (b - WP);
    else { int q = b - 2 * WP; int row = 1 + (q >> 1); pp = row * WP + ((q & 1) ? (WP - 1) : 0); }
    buf[((long long)n * HP * WP + pp) * C + c] = 0;
}

__global__ __launch_bounds__(256) void zero_chpad(unsigned short* cat)
{
    long long idx = (long long)blockIdx.x * 256 + threadIdx.x;
    if (idx >= (long long)64 * 2304 * 12) return;
    int c = 212 + (int)(idx % 12);
    long long pp = idx / 12;
    cat[pp * 224 + c] = 0;
}

__global__ __launch_bounds__(256) void out3_k(unsigned short* cat, long long loOff)
{
    long long idx = (long long)blockIdx.x * 256 + threadIdx.x;
    if (idx >= (long long)64 * 2116 * 21) return;
    int j = idx % 21; long long r = idx / 21;
    int pr = r % 2116; int n = r / 2116;
    int y = pr / 46, x = pr - y * 46;
    long long base = ((long long)n * 2304 + (y + 1) * 48 + (x + 1)) * 224;
    float a = h2f(cat[base + 3 * j])     + h2f(cat[base + 3 * j + loOff]);
    float b = h2f(cat[base + 3 * j + 1]) + h2f(cat[base + 3 * j + 1 + loOff]);
    float c = h2f(cat[base + 3 * j + 2]) + h2f(cat[base + 3 * j + 2 + loOff]);
    unsigned short vh, vl;
    split32(sqrtf(a * a + b * b + c * c), vh, vl);
    cat[base + 191 + j] = vh;
    cat[base + 191 + j + loOff] = vl;
}

__global__ __launch_bounds__(64) void argmax_hl(const unsigned short* __restrict__ h,
                                                long long loOff, float* __restrict__ outp)
{
    const int k = blockIdx.x, n = blockIdx.y, t = threadIdx.x;
    const unsigned short* b = h + (size_t)n * 2116 * 112;
    float best = -INFINITY; int ba = 0; int bb = t;
    if (t < 46) {
        for (int a = 0; a < 46; ++a) {
            int f = a * 1288 + t * 28 + k;
            int c = f / 2116, pr = f - c * 2116;
            long long e = (long long)pr * 112 + c;
            float v = h2f(b[e]) + h2f(b[e + loOff]);
            if (v > best) { best = v; ba = a; }
        }
    }
#pragma unroll
    for (int off = 32; off > 0; off >>= 1) {
        float ov = __shfl_down(best, off);
        int oa = __shfl_down(ba, off), ob = __shfl_down(bb, off);
        if (ov > best || (ov == best && ob < bb)) { best = ov; ba = oa; bb = ob; }
    }
    if (t == 0) {
        for (int q = 1; q <= 3; ++q) {
            int f = q * 59248 + ba * 1288 + bb * 28 + k;
            int c = f / 2116, pr = f - c * 2116;
            long long e = (long long)pr * 112 + c;
            outp[(size_t)n * 84 + k * 3 + (q - 1)] = h2f(b[e]) + h2f(b[e + loOff]);
        }
    }
}

// ---------------------------------------------------------------------------
extern "C" void kernel_launch(void* const* d_in, const int* in_sizes, int n_in,
                              void* d_out, int out_size, void* d_ws, size_t ws_size,
                              hipStream_t stream)
{
    const float* x   = (const float*)d_in[0];
    const float* w1  = (const float*)d_in[1];
    const float* rb1 = (const float*)d_in[2];
    const float* g1  = (const float*)d_in[3];
    const float* be1 = (const float*)d_in[4];
    const float* m1  = (const float*)d_in[5];
    const float* v1  = (const float*)d_in[6];
    const float* w2  = (const float*)d_in[7];
    const float* rb2 = (const float*)d_in[8];
    const float* g2  = (const float*)d_in[9];
    const float* be2 = (const float*)d_in[10];
    const float* m2  = (const float*)d_in[11];
    const float* v2  = (const float*)d_in[12];
    const float* w3  = (const float*)d_in[13];
    const float* rb3 = (const float*)d_in[14];
    const float* b1w = (const float*)d_in[15];
    const float* b1b = (const float*)d_in[16];
    const float* b2w = (const float*)d_in[17];
    const float* b2b = (const float*)d_in[18];
    const float* b3w = (const float*)d_in[19];
    const float* b3b = (const float*)d_in[20];
    const float* c1w = (const float*)d_in[21];
    const float* c1b = (const float*)d_in[22];
    const float* c2w = (const float*)d_in[23];
    const float* c2b = (const float*)d_in[24];
    const float* f1w = (const float*)d_in[25];
    const float* f1b = (const float*)d_in[26];
    const float* f2w = (const float*)d_in[27];
    const float* f2b = (const float*)d_in[28];

    unsigned short* wsb = (unsigned short*)d_ws;
    size_t woffE = 0;
    auto walloc = [&](size_t planeElems) {
        unsigned short* p = wsb + woffE; woffE += 2 * planeElems; return p;
    };
    unsigned short* Wr1  = walloc(524288);    // 512*1024
    unsigned short* Wr2  = walloc(2359296);   // 512*9*512
    unsigned short* Wr3  = walloc(524288);    // 1024*512
    unsigned short* Wr4  = walloc(262144);    // 256*1024
    unsigned short* Wr5  = walloc(294912);    // 128*9*256
    unsigned short* Wr6  = walloc(32768);     // 256*128
    unsigned short* Wr7  = walloc(524288);    // 128*16*256
    unsigned short* Wr8  = walloc(524288);
    unsigned short* Wr9  = walloc(258048);    // 128*9*224
    unsigned short* Wr10 = walloc(16384);     // 128*128
    char* fscr = (char*)d_ws + 23068672;
    float* s1  = (float*)(fscr);
    float* bb1 = (float*)(fscr + 2048);
    float* s2  = (float*)(fscr + 4096);
    float* bb2 = (float*)(fscr + 6144);

    unsigned short* XPU = wsb + 12582912;   // [24.0M, 162.7M) bytes
    unsigned short* R1  = wsb + 81920000;   // [163.8M, 245.8M)
    unsigned short* R2  = wsb + 12582912;
    unsigned short* R3  = wsb + 47251456;   // [94.5M, 233.2M)
    unsigned short* B1  = wsb + 116588544;  // [233.2M, 274.1M)
    unsigned short* B2  = wsb + 12582912;
    unsigned short* B3  = wsb + 21250048;   // [42.5M, 83.5M)
    unsigned short* CAT = wsb + 47251456;
    unsigned short* F1  = wsb + 12582912;
    unsigned short* F2  = wsb + 47251456;
    const long long XPU_L = 34668544, R1_L = 20480000, R2_L = 17334272, R3_L = 34668544;
    const long long B1_L = 10240000, B2_L = 4333568, B3_L = 10240000;
    const long long CAT_L = 33030144, F1_L = 17334272, F2_L = 15167488;

    prep_sb<<<1, 512, 0, stream>>>(g1, be1, m1, v1, rb1, g2, be2, m2, v2, rb2, s1, bb1, s2, bb2);
    auto pw = [&](const float* src, unsigned short* dst, long long loW, int CO, int CI,
                  int T, int COp, int CIp, const float* sc) {
        long long tot = (long long)COp * T * CIp;
        prep_w<<<(tot + 255) / 256, 256, 0, stream>>>(src, dst, loW, CO, CI, T, COp, CIp, sc);
    };
    pw(w1,  Wr1, 524288,  512, 1024, 1, 512, 1024, s1);
    pw(w2,  Wr2, 2359296, 512, 512,  9, 512, 512,  s2);
    pw(w3,  Wr3, 524288,  1024, 512, 1, 1024, 512, nullptr);
    pw(b1w, Wr4, 262144,  256, 1024, 1, 256, 1024, nullptr);
    pw(b2w, Wr5, 294912,  128, 256,  9, 128, 256,  nullptr);
    pw(b3w, Wr6, 32768,   256, 128,  1, 256, 128,  nullptr);
    prep_w_deconv<<<(128 * 16 * 256) / 256, 256, 0, stream>>>(c1w, Wr7, 524288, 63);
    prep_w_deconv<<<(128 * 16 * 256) / 256, 256, 0, stream>>>(c2w, Wr8, 524288, 128);
    pw(f1w, Wr9, 258048,  128, 212,  9, 128, 224,  nullptr);
    pw(f2w, Wr10, 16384,  112, 128,  1, 128, 128,  nullptr);
    prep_x<<<dim3(9, 16, 64), 256, 0, stream>>>(x, XPU, XPU_L);

    auto zb = [&](unsigned short* buf, long long loOff, int HP, int WP, int C) {
        int nb = 2 * WP + 2 * (HP - 2);
        long long tot = (long long)64 * nb * C;
        zero_border<<<(tot + 255) / 256, 256, 0, stream>>>(buf, HP, WP, C, nb);
        zero_border<<<(tot + 255) / 256, 256, 0, stream>>>(buf + loOff, HP, WP, C, nb);
    };

    // old-style launcher (1x1 convs)
    auto conv = [&](int NFRAG, const unsigned short* in, long long loIn,
                    const unsigned short* wr, long long loW,
                    const float* bias, const float* resx, unsigned short* outp, long long loOut,
                    int H, int W, int inWP, int inPix0, int inImg, int CIp, int T, int wRow,
                    int oImg, int oPix0, int oYstr, int oXstr, int oC, int oChOff, int CO,
                    int relu, const int* shifts, const int* woffs) {
        ConvP p{};
        p.in = in; p.wr = wr; p.bias = bias; p.resx = resx; p.out = outp;
        p.loIn = loIn; p.loW = loW; p.loOut = loOut;
        p.H = H; p.W = W; p.inWP = inWP; p.inPix0 = inPix0; p.inImg = inImg;
        p.CIp = CIp; p.T = T; p.wRow = wRow; p.pxTotal = 64 * H * W;
        p.oImg = oImg; p.oPix0 = oPix0; p.oYstr = oYstr; p.oXstr = oXstr;
        p.oC = oC; p.oChOff = oChOff; p.CO = CO;
        p.resCstr = 529; p.resImg = 541696; p.relu = relu;
        for (int t = 0; t < T; ++t) { p.shift[t] = shifts[t]; p.woff[t] = woffs[t]; }
        int BN = NFRAG * 32;
        dim3 grid((p.pxTotal + 127) / 128, (CO + BN - 1) / BN);
        if (NFRAG == 4) convmm<4><<<grid, 256, 0, stream>>>(p);
        else            convmm<2><<<grid, 256, 0, stream>>>(p);
    };

    // halo launcher (3x3 / deconv / f1)
    auto hconv = [&](int NFRAG, const unsigned short* in, long long loIn,
                     const unsigned short* wr, long long loW, const float* bias,
                     unsigned short* outp, long long loOut,
                     int W, int IMG_PX, int UNIT, int UNIT_PX, int BPI,
                     int inWP, int inPix0, int inImg,
                     int CIp, int T, int wRow,
                     int oImg, int oPix0, int oYstr, int oXstr, int oC, int oChOff, int CO,
                     int relu, const int* shifts, const int* woffs) {
        HConvP p{};
        p.in = in; p.wr = wr; p.bias = bias; p.out = outp;
        p.loIn = loIn; p.loW = loW; p.loOut = loOut;
        p.W = W; p.IMG_PX = IMG_PX; p.UNIT = UNIT; p.UNIT_PX = UNIT_PX; p.BPI = BPI;
        p.nUnits = 64 / UNIT;
        p.inWP = inWP; p.inPix0 = inPix0; p.inImg = inImg; p.halo = inWP + 1;
        p.CIp = CIp; p.T = T; p.wRow = wRow;
        p.oImg = oImg; p.oPix0 = oPix0; p.oYstr = oYstr; p.oXstr = oXstr;
        p.oC = oC; p.oChOff = oChOff; p.CO = CO; p.relu = relu;
        for (int t = 0; t < T; ++t) { p.shift[t] = shifts[t]; p.woff[t] = woffs[t]; }
        int BN = NFRAG * 32;
        int nCo = (CO + BN - 1) / BN;
        dim3 grid(nCo * p.nUnits * BPI);
        if (NFRAG == 4) convhalo<4><<<grid, 256, 0, stream>>>(p);
        else            convhalo<2><<<grid, 256, 0, stream>>>(p);
    };

    int z16[16] = {0};
    int sh9_25[16], wo9_512[16], wo9_256[16], sh9_48[16], wo9_224[16];
    for (int t = 0; t < 9; ++t) {
        int ky = t / 3, kx = t % 3;
        sh9_25[t] = (ky - 1) * 25 + (kx - 1);
        sh9_48[t] = (ky - 1) * 48 + (kx - 1);
        wo9_512[t] = t * 512; wo9_256[t] = t * 256; wo9_224[t] = t * 224;
    }

    // r5a bottleneck
    zb(R1, R1_L, 25, 25, 512);
    conv(4, XPU, XPU_L, Wr1, 524288, bb1, nullptr, R1, R1_L,
         23, 23, 23, 0, 529, 1024, 1, 1024, 625, 26, 25, 1, 512, 0, 512, 1, z16, z16);
    hconv(4, R1, R1_L, Wr2, 2359296, bb2, R2, R2_L,
          23, 529, 2, 1058, 9, 25, 26, 625, 512, 9, 9 * 512,
          529, 0, 23, 1, 512, 0, 512, 1, sh9_25, wo9_512);
    zb(B1, B1_L, 25, 25, 256);
    conv(4, R2, R2_L, Wr3, 524288, rb3, x, R3, R3_L,
         23, 23, 23, 0, 529, 512, 1, 512, 529, 0, 23, 1, 1024, 0, 1024, 0, z16, z16);
    zb(B3, B3_L, 25, 25, 256);
    conv(4, R3, R3_L, Wr4, 262144, b1b, nullptr, B1, B1_L,
         23, 23, 23, 0, 529, 1024, 1, 1024, 625, 26, 25, 1, 256, 0, 256, 0, z16, z16);
    zb(CAT, CAT_L, 48, 48, 224);
    {
        long long tot = (long long)64 * 2304 * 12;
        zero_chpad<<<(tot + 255) / 256, 256, 0, stream>>>(CAT);
        zero_chpad<<<(tot + 255) / 256, 256, 0, stream>>>(CAT + CAT_L);
    }
    hconv(4, B1, B1_L, Wr5, 294912, b2b, B2, B2_L,
          23, 529, 2, 1058, 9, 25, 26, 625, 256, 9, 9 * 256,
          529, 0, 23, 1, 128, 0, 128, 0, sh9_25, wo9_256);
    conv(4, B2, B2_L, Wr6, 32768, b3b, nullptr, B3, B3_L,
         23, 23, 23, 0, 529, 128, 1, 128, 625, 26, 25, 1, 256, 0, 256, 0, z16, z16);

    // deconvs: 4 parity classes each, B3 -> CAT (48x48 padded, C=224)
    for (int a = 0; a < 2; ++a)
        for (int b = 0; b < 2; ++b) {
            int sh[16], wo[16];
            for (int ty = 0; ty < 2; ++ty)
                for (int tx = 0; tx < 2; ++tx) {
                    int tI = ty * 2 + tx;
                    sh[tI] = (a + ty - 1) * 25 + (b + tx - 1);
                    wo[tI] = ((a + 2 * ty) * 4 + (b + 2 * tx)) * 256;
                }
            int oPix0 = (a + 1) * 48 + (b + 1);
            hconv(2, B3, B3_L, Wr7, 524288, c1b, CAT, CAT_L,
                  23, 529, 2, 1058, 9, 25, 26, 625, 256, 4, 16 * 256,
                  2304, oPix0, 96, 2, 224, 0, 63, 0, sh, wo);
            hconv(4, B3, B3_L, Wr8, 524288, c2b, CAT, CAT_L,
                  23, 529, 2, 1058, 9, 25, 26, 625, 256, 4, 16 * 256,
                  2304, oPix0, 96, 2, 224, 63, 128, 1, sh, wo);
        }
    {
        long long tot = (long long)64 * 2116 * 21;
        out3_k<<<(tot + 255) / 256, 256, 0, stream>>>(CAT, CAT_L);
    }

    // f1 / f2
    hconv(4, CAT, CAT_L, Wr9, 258048, f1b, F1, F1_L,
          46, 2116, 1, 2116, 17, 48, 49, 2304, 224, 9, 9 * 224,
          2116, 0, 46, 1, 128, 0, 128, 1, sh9_48, wo9_224);
    conv(2, F1, F1_L, Wr10, 16384, f2b, nullptr, F2, F2_L,
         46, 46, 46, 0, 2116, 128, 1, 128, 2116, 0, 46, 1, 112, 0, 112, 0, z16, z16);

    argmax_hl<<<dim3(28, 64), dim3(64), 0, stream>>>(F2, F2_L, (float*)d_out);
}